// Round 4
// baseline (315.773 us; speedup 1.0000x reference)
//
#include <hip/hip_runtime.h>
#include <math.h>

// Problem constants: B=8, L=1024, D_MODEL=512, H=8, DK=DV=64.

typedef __attribute__((ext_vector_type(4))) float f32x4;
typedef __attribute__((ext_vector_type(8))) __bf16 bf8;
typedef __attribute__((ext_vector_type(8))) unsigned short us8;
typedef __attribute__((ext_vector_type(4))) unsigned short us4;

#define LOG2E 1.44269504088896f

static __device__ __forceinline__ unsigned short f2bf(float f) {
  union { float f; unsigned u; } x; x.f = f;
  unsigned r = x.u + 0x7fffu + ((x.u >> 16) & 1u);   // RNE
  return (unsigned short)(r >> 16);
}

static __device__ __forceinline__ float bf2f(unsigned short u) {
  union { unsigned u; float f; } x; x.u = ((unsigned)u) << 16;
  return x.f;
}

static __device__ __forceinline__ f32x4 mfma16(bf8 a, bf8 b, f32x4 c) {
  return __builtin_amdgcn_mfma_f32_16x16x32_bf16(a, b, c, 0, 0, 0);
}

// ---------------- posi(h, i-j) lookup table: [8][2048], idx = (i-j)+1023 ----
// Pre-multiplied by log2(e) so attention can use exp2 directly.
__global__ void posi_build(const float* __restrict__ p0, const float* __restrict__ p1,
                           const float* __restrict__ p2, const float* __restrict__ p3,
                           float* __restrict__ tab) {
  int idx = blockIdx.x * 256 + threadIdx.x;
  if (idx >= 8 * 2048) return;
  int h = idx >> 11, dd = idx & 2047;
  if (dd >= 2047) { tab[idx] = 0.f; return; }
  float d = (float)(dd - 1023);         // d = qi - kj
  float s = fabsf(d);
  float a1 = p1[h], a2 = p2[h];
  float sp1 = (a1 > 20.f) ? a1 : log1pf(expf(a1));
  float sp2 = (a2 > 20.f) ? a2 : log1pf(expf(a2));
  float asyn = (d < 0.f) ? 1.f : 0.f;   // qi < kj
  tab[idx] = p0[h] * (expf(-sp1 * s) + expf(-sp2 * s) + p3[h] * asyn) * LOG2E;
}

// ---------------- GEMM: C[m,o] = A[m,:] . W[o,:] (+bias, epilogue) ----------
template <int EPI, bool ABF>
__global__ __launch_bounds__(256) void gemm512(
    const void* __restrict__ Ap, const float* __restrict__ W,
    const float* __restrict__ bias, unsigned short* __restrict__ outb,
    float scale, const float* __restrict__ resid, float* __restrict__ outf) {
  __shared__ __align__(16) unsigned short As[128 * 32];
  __shared__ __align__(16) unsigned short Bs[128 * 32];
  const int tid = threadIdx.x;
  const int lane = tid & 63, w = tid >> 6;
  const int lg = lane >> 4, ln = lane & 15;
  const int wr = w >> 1, wc = w & 1;
  const int bm = blockIdx.x, bn = blockIdx.y;

  f32x4 acc[4][4] = {};

  for (int kt = 0; kt < 16; ++kt) {
    const int k0 = kt * 32;
    f32x4 areg[4]; us8 areg16[2]; f32x4 breg[4];
    if constexpr (!ABF) {
      const float* A = (const float*)Ap;
#pragma unroll
      for (int i = 0; i < 4; ++i) {
        int e = i * 1024 + tid * 4;
        int r = e >> 5, c = e & 31;
        areg[i] = *(const f32x4*)(A + (size_t)(bm * 128 + r) * 512 + k0 + c);
      }
    } else {
      const unsigned short* A = (const unsigned short*)Ap;
#pragma unroll
      for (int i = 0; i < 2; ++i) {
        int ch = i * 256 + tid;
        int r = ch >> 2, c = (ch & 3) * 8;
        areg16[i] = *(const us8*)(A + (size_t)(bm * 128 + r) * 512 + k0 + c);
      }
    }
#pragma unroll
    for (int i = 0; i < 4; ++i) {
      int e = i * 1024 + tid * 4;
      int r = e >> 5, c = e & 31;
      breg[i] = *(const f32x4*)(W + (size_t)(bn * 128 + r) * 512 + k0 + c);
    }
    __syncthreads();
    if constexpr (!ABF) {
#pragma unroll
      for (int i = 0; i < 4; ++i) {
        int e = i * 1024 + tid * 4;
        int r = e >> 5, c = e & 31;
        us4 u; u[0] = f2bf(areg[i][0]); u[1] = f2bf(areg[i][1]);
        u[2] = f2bf(areg[i][2]); u[3] = f2bf(areg[i][3]);
        *(us4*)&As[r * 32 + c] = u;
      }
    } else {
#pragma unroll
      for (int i = 0; i < 2; ++i) {
        int ch = i * 256 + tid;
        int r = ch >> 2, c = (ch & 3) * 8;
        *(us8*)&As[r * 32 + c] = areg16[i];
      }
    }
#pragma unroll
    for (int i = 0; i < 4; ++i) {
      int e = i * 1024 + tid * 4;
      int r = e >> 5, c = e & 31;
      us4 u; u[0] = f2bf(breg[i][0]); u[1] = f2bf(breg[i][1]);
      u[2] = f2bf(breg[i][2]); u[3] = f2bf(breg[i][3]);
      *(us4*)&Bs[r * 32 + c] = u;
    }
    __syncthreads();
    bf8 af[4], bfm[4];
#pragma unroll
    for (int m = 0; m < 4; ++m)
      af[m] = *(const bf8*)&As[(wr * 64 + m * 16 + ln) * 32 + lg * 8];
#pragma unroll
    for (int n = 0; n < 4; ++n)
      bfm[n] = *(const bf8*)&Bs[(wc * 64 + n * 16 + ln) * 32 + lg * 8];
#pragma unroll
    for (int m = 0; m < 4; ++m)
#pragma unroll
      for (int n = 0; n < 4; ++n)
        acc[m][n] = mfma16(af[m], bfm[n], acc[m][n]);
  }

#pragma unroll
  for (int m = 0; m < 4; ++m) {
#pragma unroll
    for (int n = 0; n < 4; ++n) {
      const int col = bn * 128 + wc * 64 + n * 16 + ln;
      const int row0 = bm * 128 + wr * 64 + m * 16 + lg * 4;
      const float bcol = bias[col];
#pragma unroll
      for (int r = 0; r < 4; ++r) {
        const int rg = row0 + r;
        float val = acc[m][n][r];
        if constexpr (EPI == 0) {
          val = (val + bcol) * scale;
          const int bb = rg >> 10, lq = rg & 1023, hh = col >> 6, dd = col & 63;
          outb[((size_t)(bb * 8 + hh) * 1024 + lq) * 64 + dd] = f2bf(val);
        } else {
          val = val + bcol + resid[(size_t)rg * 512 + col];
          outf[(size_t)rg * 512 + col] = val;
        }
      }
    }
  }
}

// ---------------- V transpose: [bh][l][d] -> [bh][d][l] --------------------
__global__ __launch_bounds__(256) void transpose_v(const unsigned short* __restrict__ VH,
                                                   unsigned short* __restrict__ VT) {
  __shared__ __align__(16) unsigned short t[64][72];
  const int bh = blockIdx.y;
  const int l0 = blockIdx.x * 64;
  const unsigned short* src = VH + ((size_t)bh * 1024 + l0) * 64;
#pragma unroll
  for (int i = 0; i < 2; ++i) {
    int ch = i * 256 + threadIdx.x;
    int r = ch >> 3, c8 = ch & 7;
    *(us8*)&t[r][c8 * 8] = *(const us8*)(src + r * 64 + c8 * 8);
  }
  __syncthreads();
  unsigned short* dst = VT + (size_t)bh * 64 * 1024 + l0;
#pragma unroll
  for (int i = 0; i < 2; ++i) {
    int ch = i * 256 + threadIdx.x;
    int d = ch >> 3, l8 = ch & 7;
    us8 vv;
#pragma unroll
    for (int j = 0; j < 8; ++j) vv[j] = t[l8 * 8 + j][d];
    *(us8*)(dst + (size_t)d * 1024 + l8 * 8) = vv;
  }
}

// ---------------- fused attention (swapped QK^T, kj-split waves) -----------
// grid 2048: wgid = qblk*64 + bh  (bh = wgid&63 -> XCD = bh&7, L2-resident K/V).
// WG = 4 waves: wave w -> strip s = w>>1 (16 q-rows), kj-half kh = w&1 (512 kj).
// 8192 waves total = 100% occupancy potential (vs 4096 = 50% before).
// Pass A: partial row-sums of exp2, combined across kh pair via lred.
// Pass B: normalized bf16 P -> p_lds, PV partial, gathered attn store; partial
// oacc combined across kh pair via LDS (overlaid on p_lds after barrier).
__global__ __launch_bounds__(256, 8) void attn_fwd(
    const unsigned short* __restrict__ QH, const unsigned short* __restrict__ KH,
    const unsigned short* __restrict__ VT, const float* __restrict__ posi_tab,
    float* __restrict__ attn_out, unsigned short* __restrict__ Omat) {
  __shared__ float posi_s[2048];
  __shared__ __align__(16) unsigned short p_lds[4][16][80];   // 160B rows; also osum overlay
  __shared__ float lred[4][16];

  const int tid = threadIdx.x;
  const int lane = tid & 63, w = tid >> 6;
  const int lg = lane >> 4, ln = lane & 15;
  const int s = w >> 1, kh = w & 1;
  const int wgid = blockIdx.x;
  const int bh = wgid & 63, qblk = wgid >> 6;
  const int b = bh >> 3, h = bh & 7;

  for (int i = tid; i < 2048; i += 256) posi_s[i] = posi_tab[h * 2048 + i];
  __syncthreads();

  const int q0 = qblk * 32 + s * 16;      // this wave's q-strip
  const int kbase = kh << 9;              // this wave's kj-half base
  const size_t base = (size_t)(b * 8 + h) * 1024 * 64;
  const unsigned short* Qb = QH + base;
  const unsigned short* Kb = KH + base;
  const unsigned short* Vb = VT + base;

  const int qi = q0 + ln;                 // this lane's q-row
  // Q b-fragments (Q pre-scaled by log2e/sqrt(dk) in projection epilogue)
  const bf8 bq0 = *(const bf8*)(Qb + (size_t)qi * 64 + lg * 8);
  const bf8 bq1 = *(const bf8*)(Qb + (size_t)qi * 64 + lg * 8 + 32);

  // ---- PASS A: partial row sum of exp2 over this wave's kj half ----
  float lacc = 0.f;
  for (int kt = 0; kt < 8; ++kt) {
    const int k0 = kbase + kt * 64;
#pragma unroll
    for (int n = 0; n < 4; ++n) {
      const unsigned short* kr = Kb + (size_t)(k0 + n * 16 + ln) * 64 + lg * 8;
      bf8 a0 = *(const bf8*)kr;
      bf8 a1 = *(const bf8*)(kr + 32);
      f32x4 sc = {};
      sc = mfma16(a0, bq0, sc);
      sc = mfma16(a1, bq1, sc);
      const int pidx = qi - (k0 + n * 16 + lg * 4) + 1023;
#pragma unroll
      for (int r = 0; r < 4; ++r)
        lacc += exp2f(sc[r] + posi_s[pidx - r]);
    }
  }
  lacc += __shfl_xor(lacc, 16, 64);
  lacc += __shfl_xor(lacc, 32, 64);
  if (lg == 0) lred[w][ln] = lacc;
  __syncthreads();
  const float rl = 1.f / (lred[s * 2][ln] + lred[s * 2 + 1][ln]);

  // ---- PASS B: normalized probs (bf16) -> p_lds; PV; gathered attn store --
  f32x4 oacc[4] = {};
  float* abb = attn_out + (size_t)(h * 8 + b) * 1024 * 1024;

  for (int kt = 0; kt < 8; ++kt) {
    const int k0 = kbase + kt * 64;
#pragma unroll
    for (int n = 0; n < 4; ++n) {
      const unsigned short* kr = Kb + (size_t)(k0 + n * 16 + ln) * 64 + lg * 8;
      bf8 a0 = *(const bf8*)kr;
      bf8 a1 = *(const bf8*)(kr + 32);
      f32x4 sc = {};
      sc = mfma16(a0, bq0, sc);
      sc = mfma16(a1, bq1, sc);
      const int kcol = n * 16 + lg * 4;
      const int pidx = qi - (k0 + kcol) + 1023;
      us4 pb;
#pragma unroll
      for (int r = 0; r < 4; ++r)
        pb[r] = f2bf(exp2f(sc[r] + posi_s[pidx - r]) * rl);
      *(us4*)&p_lds[w][ln][kcol] = pb;                     // ds_write_b64
    }
    // A-fragments for PV: P[qi=ln][kj = win*32 + lg*8 + j]
    const bf8 pa0 = *(const bf8*)&p_lds[w][ln][lg * 8];
    const bf8 pa1 = *(const bf8*)&p_lds[w][ln][32 + lg * 8];
#pragma unroll
    for (int n = 0; n < 4; ++n) {
      const unsigned short* vr = Vb + (size_t)(n * 16 + ln) * 1024 + k0 + lg * 8;
      bf8 v0 = *(const bf8*)vr;
      bf8 v1 = *(const bf8*)(vr + 32);
      oacc[n] = mfma16(pa0, v0, oacc[n]);
      oacc[n] = mfma16(pa1, v1, oacc[n]);
    }
    // Gathered attn store: per instr 4 rows x 256B contiguous segments.
#pragma unroll
    for (int j = 0; j < 4; ++j) {
      const int r = j * 4 + lg;
      const int c4 = ln * 4;
      us4 pv = *(const us4*)&p_lds[w][r][c4];
      f32x4 o;
#pragma unroll
      for (int t = 0; t < 4; ++t) o[t] = bf2f(pv[t]);
      *(f32x4*)(abb + (size_t)(q0 + r) * 1024 + k0 + c4) = o;
    }
  }

  // ---- combine partial PV across the kh pair (overlay osum on p_lds) ----
  __syncthreads();                         // all p_lds reads done
  float* osum = (float*)p_lds;             // [2 strips][64 lanes][16 floats]
  if (kh == 1) {
#pragma unroll
    for (int n = 0; n < 4; ++n)
      *(f32x4*)&osum[((size_t)s * 64 + lane) * 16 + n * 4] = oacc[n];
  }
  __syncthreads();
  if (kh == 0) {
#pragma unroll
    for (int n = 0; n < 4; ++n) {
      f32x4 other = *(const f32x4*)&osum[((size_t)s * 64 + lane) * 16 + n * 4];
      oacc[n] += other;
#pragma unroll
      for (int r = 0; r < 4; ++r)
        Omat[(size_t)(b * 1024 + q0 + lg * 4 + r) * 512 + h * 64 + n * 16 + ln] =
            f2bf(oacc[n][r]);
    }
  }
}

// ---------------- LayerNorm over 512, one wave per row ---------------------
__global__ __launch_bounds__(256) void ln_fused(const float* __restrict__ x,
                                                const float* __restrict__ g,
                                                const float* __restrict__ bb,
                                                float* __restrict__ out) {
  const int lane = threadIdx.x & 63, w = threadIdx.x >> 6;
  const size_t row = (size_t)blockIdx.x * 4 + w;
  const float* xr = x + row * 512;
  f32x4 v0 = *(const f32x4*)(xr + lane * 8);
  f32x4 v1 = *(const f32x4*)(xr + lane * 8 + 4);
  float s = v0[0] + v0[1] + v0[2] + v0[3] + v1[0] + v1[1] + v1[2] + v1[3];
  float sq = v0[0] * v0[0] + v0[1] * v0[1] + v0[2] * v0[2] + v0[3] * v0[3] +
             v1[0] * v1[0] + v1[1] * v1[1] + v1[2] * v1[2] + v1[3] * v1[3];
#pragma unroll
  for (int msk = 1; msk <= 32; msk <<= 1) {
    s += __shfl_xor(s, msk, 64);
    sq += __shfl_xor(sq, msk, 64);
  }
  const float mu = s * (1.f / 512.f);
  const float var = sq * (1.f / 512.f) - mu * mu;
  const float rs = rsqrtf(var + 1e-5f);
  f32x4 g0 = *(const f32x4*)(g + lane * 8), g1 = *(const f32x4*)(g + lane * 8 + 4);
  f32x4 b0 = *(const f32x4*)(bb + lane * 8), b1 = *(const f32x4*)(bb + lane * 8 + 4);
  f32x4 o0, o1;
#pragma unroll
  for (int j = 0; j < 4; ++j) {
    o0[j] = (v0[j] - mu) * rs * g0[j] + b0[j];
    o1[j] = (v1[j] - mu) * rs * g1[j] + b1[j];
  }
  *(f32x4*)(out + row * 512 + lane * 8) = o0;
  *(f32x4*)(out + row * 512 + lane * 8 + 4) = o1;
}

extern "C" void kernel_launch(void* const* d_in, const int* in_sizes, int n_in,
                              void* d_out, int out_size, void* d_ws, size_t ws_size,
                              hipStream_t stream) {
  const float* q   = (const float*)d_in[0];
  const float* k   = (const float*)d_in[1];
  const float* v   = (const float*)d_in[2];
  const float* wqW = (const float*)d_in[3];
  const float* wqb = (const float*)d_in[4];
  const float* wkW = (const float*)d_in[5];
  const float* wkb = (const float*)d_in[6];
  const float* wvW = (const float*)d_in[7];
  const float* wvb = (const float*)d_in[8];
  const float* fcW = (const float*)d_in[9];
  const float* fcb = (const float*)d_in[10];
  const float* lng = (const float*)d_in[11];
  const float* lnb = (const float*)d_in[12];
  const float* p0  = (const float*)d_in[13];
  const float* p1  = (const float*)d_in[14];
  const float* p2  = (const float*)d_in[15];
  const float* p3  = (const float*)d_in[16];

  char* ws = (char*)d_ws;
  unsigned short* QH   = (unsigned short*)(ws);              //  8 MiB  [b][h][l][64] bf16
  unsigned short* KH   = (unsigned short*)(ws + 8388608);    //  8 MiB
  unsigned short* VH   = (unsigned short*)(ws + 16777216);   //  8 MiB
  unsigned short* VT   = (unsigned short*)(ws + 25165824);   //  8 MiB  [b][h][64][l]
  unsigned short* Omat = (unsigned short*)(ws + 33554432);   //  8 MiB  [b*l][512] bf16
  float* posi          = (float*)(ws + 41943040);            // 64 KiB
  float* preln         = (float*)(ws + 42008576);            // 16 MiB  fp32

  float* out0 = (float*)d_out;
  float* attn = out0 + (size_t)8 * 1024 * 512;

  posi_build<<<64, 256, 0, stream>>>(p0, p1, p2, p3, posi);
  // Q projection pre-scaled by log2(e)/sqrt(64) so attn uses exp2 directly.
  gemm512<0, false><<<dim3(64, 4), 256, 0, stream>>>(q, wqW, wqb, QH, 0.125f * LOG2E, nullptr, nullptr);
  gemm512<0, false><<<dim3(64, 4), 256, 0, stream>>>(k, wkW, wkb, KH, 1.f, nullptr, nullptr);
  gemm512<0, false><<<dim3(64, 4), 256, 0, stream>>>(v, wvW, wvb, VH, 1.f, nullptr, nullptr);
  transpose_v<<<dim3(16, 64), 256, 0, stream>>>(VH, VT);
  attn_fwd<<<2048, 256, 0, stream>>>(QH, KH, VT, posi, attn, Omat);
  gemm512<1, true><<<dim3(64, 4), 256, 0, stream>>>(Omat, fcW, fcb, nullptr, 1.f, q, preln);
  ln_fused<<<2048, 256, 0, stream>>>(preln, lng, lnb, out0);
}

// Round 7
// 301.411 us; speedup vs baseline: 1.0476x; 1.0476x over previous
//
#include <hip/hip_runtime.h>
#include <math.h>

// Problem constants: B=8, L=1024, D_MODEL=512, H=8, DK=DV=64.

typedef __attribute__((ext_vector_type(4))) float f32x4;
typedef __attribute__((ext_vector_type(8))) __bf16 bf8;
typedef __attribute__((ext_vector_type(8))) unsigned short us8;
typedef __attribute__((ext_vector_type(4))) unsigned short us4;

#define LOG2E 1.44269504088896f

static __device__ __forceinline__ unsigned short f2bf(float f) {
  union { float f; unsigned u; } x; x.f = f;
  unsigned r = x.u + 0x7fffu + ((x.u >> 16) & 1u);   // RNE
  return (unsigned short)(r >> 16);
}

static __device__ __forceinline__ float bf2f(unsigned short u) {
  union { unsigned u; float f; } x; x.u = ((unsigned)u) << 16;
  return x.f;
}

static __device__ __forceinline__ f32x4 mfma16(bf8 a, bf8 b, f32x4 c) {
  return __builtin_amdgcn_mfma_f32_16x16x32_bf16(a, b, c, 0, 0, 0);
}

// ---------------- posi(h, i-j) lookup table: [8][2048], idx = (i-j)+1023 ----
// Pre-multiplied by log2(e) so attention can use exp2 directly.
__global__ void posi_build(const float* __restrict__ p0, const float* __restrict__ p1,
                           const float* __restrict__ p2, const float* __restrict__ p3,
                           float* __restrict__ tab) {
  int idx = blockIdx.x * 256 + threadIdx.x;
  if (idx >= 8 * 2048) return;
  int h = idx >> 11, dd = idx & 2047;
  if (dd >= 2047) { tab[idx] = 0.f; return; }
  float d = (float)(dd - 1023);         // d = qi - kj
  float s = fabsf(d);
  float a1 = p1[h], a2 = p2[h];
  float sp1 = (a1 > 20.f) ? a1 : log1pf(expf(a1));
  float sp2 = (a2 > 20.f) ? a2 : log1pf(expf(a2));
  float asyn = (d < 0.f) ? 1.f : 0.f;   // qi < kj
  tab[idx] = p0[h] * (expf(-sp1 * s) + expf(-sp2 * s) + p3[h] * asyn) * LOG2E;
}

// ---------------- GEMM: C[m,o] = A[m,:] . W[o,:] (+bias, epilogue) ----------
template <int EPI, bool ABF>
__global__ __launch_bounds__(256) void gemm512(
    const void* __restrict__ Ap, const float* __restrict__ W,
    const float* __restrict__ bias, unsigned short* __restrict__ outb,
    float scale, const float* __restrict__ resid, float* __restrict__ outf) {
  __shared__ __align__(16) unsigned short As[128 * 32];
  __shared__ __align__(16) unsigned short Bs[128 * 32];
  const int tid = threadIdx.x;
  const int lane = tid & 63, w = tid >> 6;
  const int lg = lane >> 4, ln = lane & 15;
  const int wr = w >> 1, wc = w & 1;
  const int bm = blockIdx.x, bn = blockIdx.y;

  f32x4 acc[4][4] = {};

  for (int kt = 0; kt < 16; ++kt) {
    const int k0 = kt * 32;
    f32x4 areg[4]; us8 areg16[2]; f32x4 breg[4];
    if constexpr (!ABF) {
      const float* A = (const float*)Ap;
#pragma unroll
      for (int i = 0; i < 4; ++i) {
        int e = i * 1024 + tid * 4;
        int r = e >> 5, c = e & 31;
        areg[i] = *(const f32x4*)(A + (size_t)(bm * 128 + r) * 512 + k0 + c);
      }
    } else {
      const unsigned short* A = (const unsigned short*)Ap;
#pragma unroll
      for (int i = 0; i < 2; ++i) {
        int ch = i * 256 + tid;
        int r = ch >> 2, c = (ch & 3) * 8;
        areg16[i] = *(const us8*)(A + (size_t)(bm * 128 + r) * 512 + k0 + c);
      }
    }
#pragma unroll
    for (int i = 0; i < 4; ++i) {
      int e = i * 1024 + tid * 4;
      int r = e >> 5, c = e & 31;
      breg[i] = *(const f32x4*)(W + (size_t)(bn * 128 + r) * 512 + k0 + c);
    }
    __syncthreads();
    if constexpr (!ABF) {
#pragma unroll
      for (int i = 0; i < 4; ++i) {
        int e = i * 1024 + tid * 4;
        int r = e >> 5, c = e & 31;
        us4 u; u[0] = f2bf(areg[i][0]); u[1] = f2bf(areg[i][1]);
        u[2] = f2bf(areg[i][2]); u[3] = f2bf(areg[i][3]);
        *(us4*)&As[r * 32 + c] = u;
      }
    } else {
#pragma unroll
      for (int i = 0; i < 2; ++i) {
        int ch = i * 256 + tid;
        int r = ch >> 2, c = (ch & 3) * 8;
        *(us8*)&As[r * 32 + c] = areg16[i];
      }
    }
#pragma unroll
    for (int i = 0; i < 4; ++i) {
      int e = i * 1024 + tid * 4;
      int r = e >> 5, c = e & 31;
      us4 u; u[0] = f2bf(breg[i][0]); u[1] = f2bf(breg[i][1]);
      u[2] = f2bf(breg[i][2]); u[3] = f2bf(breg[i][3]);
      *(us4*)&Bs[r * 32 + c] = u;
    }
    __syncthreads();
    bf8 af[4], bfm[4];
#pragma unroll
    for (int m = 0; m < 4; ++m)
      af[m] = *(const bf8*)&As[(wr * 64 + m * 16 + ln) * 32 + lg * 8];
#pragma unroll
    for (int n = 0; n < 4; ++n)
      bfm[n] = *(const bf8*)&Bs[(wc * 64 + n * 16 + ln) * 32 + lg * 8];
#pragma unroll
    for (int m = 0; m < 4; ++m)
#pragma unroll
      for (int n = 0; n < 4; ++n)
        acc[m][n] = mfma16(af[m], bfm[n], acc[m][n]);
  }

#pragma unroll
  for (int m = 0; m < 4; ++m) {
#pragma unroll
    for (int n = 0; n < 4; ++n) {
      const int col = bn * 128 + wc * 64 + n * 16 + ln;
      const int row0 = bm * 128 + wr * 64 + m * 16 + lg * 4;
      const float bcol = bias[col];
#pragma unroll
      for (int r = 0; r < 4; ++r) {
        const int rg = row0 + r;
        float val = acc[m][n][r];
        if constexpr (EPI == 0) {
          val = (val + bcol) * scale;
          const int bb = rg >> 10, lq = rg & 1023, hh = col >> 6, dd = col & 63;
          outb[((size_t)(bb * 8 + hh) * 1024 + lq) * 64 + dd] = f2bf(val);
        } else {
          val = val + bcol + resid[(size_t)rg * 512 + col];
          outf[(size_t)rg * 512 + col] = val;
        }
      }
    }
  }
}

// ---------------- V transpose: [bh][l][d] -> [bh][d][l] --------------------
__global__ __launch_bounds__(256) void transpose_v(const unsigned short* __restrict__ VH,
                                                   unsigned short* __restrict__ VT) {
  __shared__ __align__(16) unsigned short t[64][72];
  const int bh = blockIdx.y;
  const int l0 = blockIdx.x * 64;
  const unsigned short* src = VH + ((size_t)bh * 1024 + l0) * 64;
#pragma unroll
  for (int i = 0; i < 2; ++i) {
    int ch = i * 256 + threadIdx.x;
    int r = ch >> 3, c8 = ch & 7;
    *(us8*)&t[r][c8 * 8] = *(const us8*)(src + r * 64 + c8 * 8);
  }
  __syncthreads();
  unsigned short* dst = VT + (size_t)bh * 64 * 1024 + l0;
#pragma unroll
  for (int i = 0; i < 2; ++i) {
    int ch = i * 256 + threadIdx.x;
    int d = ch >> 3, l8 = ch & 7;
    us8 vv;
#pragma unroll
    for (int j = 0; j < 8; ++j) vv[j] = t[l8 * 8 + j][d];
    *(us8*)(dst + (size_t)d * 1024 + l8 * 8) = vv;
  }
}

// ---------------- attention core: single pass, unnormalized P --------------
// grid 1024: wgid = qblk*64 + bh (bh&7 = XCD -> L2-resident K/V slab).
// WG = 4 waves: wave (sp = w>>1, kh = w&1): 2 q-strips of 16 rows, kj-half kh.
// Scores layout: lane(lg,ln) reg r holds S[q=ln][kj=lg*4+r] (q-row = ln).
// PV output layout: lane(lg,ln) reg r holds O[q=lg*4+r][d=n*16+ln]
// (q-row = lg*4+r != ln -- the R5/R6 bug was normalizing O with rl[ln]).
template <bool PBF16>
__global__ __launch_bounds__(256) void attn_core(
    const unsigned short* __restrict__ QH, const unsigned short* __restrict__ KH,
    const unsigned short* __restrict__ VT, const float* __restrict__ posi_tab,
    void* __restrict__ pstore, float* __restrict__ Lrow,
    unsigned short* __restrict__ Omat) {
  __shared__ float posi_s[2048];
  __shared__ __align__(16) unsigned short p_lds[4][2][16][80];  // 20.5 KB
  __shared__ float lred[4][2][16];

  const int tid = threadIdx.x;
  const int lane = tid & 63, w = tid >> 6;
  const int lg = lane >> 4, ln = lane & 15;
  const int sp = w >> 1, kh = w & 1;
  const int wgid = blockIdx.x;
  const int bh = wgid & 63, qblk = wgid >> 6;
  const int b = bh >> 3, h = bh & 7;

  for (int i = tid; i < 2048; i += 256) posi_s[i] = posi_tab[h * 2048 + i];
  __syncthreads();

  const int qbase = qblk * 64 + sp * 32;
  const int kbase = kh << 9;
  const int slab = h * 8 + b;
  const size_t base = (size_t)(b * 8 + h) * 1024 * 64;
  const unsigned short* Qb = QH + base;
  const unsigned short* Kb = KH + base;
  const unsigned short* Vb = VT + base;

  // Q b-fragments for 2 strips (Q pre-scaled by log2e/8 in projection)
  bf8 bq[2][2];
#pragma unroll
  for (int st = 0; st < 2; ++st) {
    const unsigned short* qr = Qb + (size_t)(qbase + st * 16 + ln) * 64 + lg * 8;
    bq[st][0] = *(const bf8*)qr;
    bq[st][1] = *(const bf8*)(qr + 32);
  }

  float lacc[2] = {0.f, 0.f};
  f32x4 oacc[2][4] = {};

  for (int kt = 0; kt < 8; ++kt) {
    const int k0 = kbase + kt * 64;
    // --- scores + exp2 for 64 kj x 32 q-rows ---
#pragma unroll
    for (int n = 0; n < 4; ++n) {
      const unsigned short* kr = Kb + (size_t)(k0 + n * 16 + ln) * 64 + lg * 8;
      bf8 a0 = *(const bf8*)kr;
      bf8 a1 = *(const bf8*)(kr + 32);
#pragma unroll
      for (int st = 0; st < 2; ++st) {
        f32x4 sc = {};
        sc = mfma16(a0, bq[st][0], sc);
        sc = mfma16(a1, bq[st][1], sc);
        const int qi = qbase + st * 16 + ln;
        const int pidx = qi - (k0 + n * 16 + lg * 4) + 1023;
        us4 pb;
#pragma unroll
        for (int r = 0; r < 4; ++r) {
          float p = exp2f(sc[r] + posi_s[pidx - r]);
          lacc[st] += p;
          pb[r] = f2bf(p);
        }
        *(us4*)&p_lds[w][st][ln][n * 16 + lg * 4] = pb;
      }
    }
    // --- PV: A-fragments from p_lds, shared V-loads ---
    bf8 pa[2][2];
#pragma unroll
    for (int st = 0; st < 2; ++st) {
      pa[st][0] = *(const bf8*)&p_lds[w][st][ln][lg * 8];
      pa[st][1] = *(const bf8*)&p_lds[w][st][ln][32 + lg * 8];
    }
#pragma unroll
    for (int n = 0; n < 4; ++n) {
      const unsigned short* vr = Vb + (size_t)(n * 16 + ln) * 1024 + k0 + lg * 8;
      bf8 v0 = *(const bf8*)vr;
      bf8 v1 = *(const bf8*)(vr + 32);
#pragma unroll
      for (int st = 0; st < 2; ++st) {
        oacc[st][n] = mfma16(pa[st][0], v0, oacc[st][n]);
        oacc[st][n] = mfma16(pa[st][1], v1, oacc[st][n]);
      }
    }
    // --- unnormalized P store (gathered: 8 rows x 128B segments / instr) ---
#pragma unroll
    for (int st = 0; st < 2; ++st) {
#pragma unroll
      for (int j = 0; j < 2; ++j) {
        const int row_l = j * 8 + (lane >> 3);
        const int col8 = (lane & 7) * 8;
        us8 pv = *(const us8*)&p_lds[w][st][row_l][col8];
        const size_t prow = (size_t)slab * 1024 + qbase + st * 16 + row_l;
        if constexpr (PBF16) {
          *(us8*)((unsigned short*)pstore + prow * 1024 + k0 + col8) = pv;
        } else {
          float* ap = (float*)pstore + prow * 1024 + k0 + col8;
          f32x4 f0, f1;
#pragma unroll
          for (int t = 0; t < 4; ++t) { f0[t] = bf2f(pv[t]); f1[t] = bf2f(pv[t + 4]); }
          *(f32x4*)ap = f0;
          *(f32x4*)(ap + 4) = f1;
        }
      }
    }
  }

  // ---- epilogue: combine l and O across the kh pair ----
  lacc[0] += __shfl_xor(lacc[0], 16, 64);
  lacc[0] += __shfl_xor(lacc[0], 32, 64);
  lacc[1] += __shfl_xor(lacc[1], 16, 64);
  lacc[1] += __shfl_xor(lacc[1], 32, 64);
  if (lg == 0) { lred[w][0][ln] = lacc[0]; lred[w][1][ln] = lacc[1]; }

  // osum overlays p_lds across ALL waves' regions; every wave must be done
  // with its main-loop p_lds reads before any overlay write.
  __syncthreads();

  f32x4* osum = (f32x4*)p_lds;   // overlay: [ (sp*2+st)*64 + lane ][n], 16 KB
  if (kh == 1) {
#pragma unroll
    for (int st = 0; st < 2; ++st)
#pragma unroll
      for (int n = 0; n < 4; ++n)
        osum[((sp * 2 + st) * 64 + lane) * 4 + n] = oacc[st][n];
  }
  __syncthreads();
  if (kh == 0) {
#pragma unroll
    for (int st = 0; st < 2; ++st) {
      // Lrow (attn normalization) is per scores-layout row = ln.
      if (lg == 0)
        Lrow[(size_t)slab * 1024 + qbase + st * 16 + ln] =
            1.f / (lred[sp * 2][st][ln] + lred[sp * 2 + 1][st][ln]);
      // BUG FIX (R5/R6): O fragment rows are lg*4+r, not ln. Normalize each
      // register with ITS row's denominator.
      f32x4 rlv;
#pragma unroll
      for (int r = 0; r < 4; ++r)
        rlv[r] = 1.f / (lred[sp * 2][st][lg * 4 + r] + lred[sp * 2 + 1][st][lg * 4 + r]);
#pragma unroll
      for (int n = 0; n < 4; ++n) {
        f32x4 o = oacc[st][n] + osum[((sp * 2 + st) * 64 + lane) * 4 + n];
#pragma unroll
        for (int r = 0; r < 4; ++r)
          Omat[(size_t)(b * 1024 + qbase + st * 16 + lg * 4 + r) * 512 +
               h * 64 + n * 16 + ln] = f2bf(o[r] * rlv[r]);
      }
    }
  }
}

// ---------------- normalize: attn = P * rl (streaming) ---------------------
template <bool INPLACE>
__global__ __launch_bounds__(256) void attn_norm(const unsigned short* __restrict__ Pmat,
                                                 const float* __restrict__ Lrow,
                                                 float* __restrict__ attn) {
  const size_t total = (size_t)64 * 1024 * 1024;
  const size_t stride = (size_t)gridDim.x * 256 * 8;
  for (size_t i = ((size_t)blockIdx.x * 256 + threadIdx.x) * 8; i < total; i += stride) {
    const float rl = Lrow[i >> 10];
    f32x4 a0, a1;
    if constexpr (INPLACE) {
      a0 = *(const f32x4*)(attn + i);
      a1 = *(const f32x4*)(attn + i + 4);
#pragma unroll
      for (int j = 0; j < 4; ++j) { a0[j] *= rl; a1[j] *= rl; }
    } else {
      us8 pv = *(const us8*)(Pmat + i);
#pragma unroll
      for (int j = 0; j < 4; ++j) { a0[j] = bf2f(pv[j]) * rl; a1[j] = bf2f(pv[j + 4]) * rl; }
    }
    *(f32x4*)(attn + i) = a0;
    *(f32x4*)(attn + i + 4) = a1;
  }
}

// ---------------- LayerNorm over 512, one wave per row ---------------------
__global__ __launch_bounds__(256) void ln_fused(const float* __restrict__ x,
                                                const float* __restrict__ g,
                                                const float* __restrict__ bb,
                                                float* __restrict__ out) {
  const int lane = threadIdx.x & 63, w = threadIdx.x >> 6;
  const size_t row = (size_t)blockIdx.x * 4 + w;
  const float* xr = x + row * 512;
  f32x4 v0 = *(const f32x4*)(xr + lane * 8);
  f32x4 v1 = *(const f32x4*)(xr + lane * 8 + 4);
  float s = v0[0] + v0[1] + v0[2] + v0[3] + v1[0] + v1[1] + v1[2] + v1[3];
  float sq = v0[0] * v0[0] + v0[1] * v0[1] + v0[2] * v0[2] + v0[3] * v0[3] +
             v1[0] * v1[0] + v1[1] * v1[1] + v1[2] * v1[2] + v1[3] * v1[3];
#pragma unroll
  for (int msk = 1; msk <= 32; msk <<= 1) {
    s += __shfl_xor(s, msk, 64);
    sq += __shfl_xor(sq, msk, 64);
  }
  const float mu = s * (1.f / 512.f);
  const float var = sq * (1.f / 512.f) - mu * mu;
  const float rs = rsqrtf(var + 1e-5f);
  f32x4 g0 = *(const f32x4*)(g + lane * 8), g1 = *(const f32x4*)(g + lane * 8 + 4);
  f32x4 b0 = *(const f32x4*)(bb + lane * 8), b1 = *(const f32x4*)(bb + lane * 8 + 4);
  f32x4 o0, o1;
#pragma unroll
  for (int j = 0; j < 4; ++j) {
    o0[j] = (v0[j] - mu) * rs * g0[j] + b0[j];
    o1[j] = (v1[j] - mu) * rs * g1[j] + b1[j];
  }
  *(f32x4*)(out + row * 512 + lane * 8) = o0;
  *(f32x4*)(out + row * 512 + lane * 8 + 4) = o1;
}

extern "C" void kernel_launch(void* const* d_in, const int* in_sizes, int n_in,
                              void* d_out, int out_size, void* d_ws, size_t ws_size,
                              hipStream_t stream) {
  const float* q   = (const float*)d_in[0];
  const float* k   = (const float*)d_in[1];
  const float* v   = (const float*)d_in[2];
  const float* wqW = (const float*)d_in[3];
  const float* wqb = (const float*)d_in[4];
  const float* wkW = (const float*)d_in[5];
  const float* wkb = (const float*)d_in[6];
  const float* wvW = (const float*)d_in[7];
  const float* wvb = (const float*)d_in[8];
  const float* fcW = (const float*)d_in[9];
  const float* fcb = (const float*)d_in[10];
  const float* lng = (const float*)d_in[11];
  const float* lnb = (const float*)d_in[12];
  const float* p0  = (const float*)d_in[13];
  const float* p1  = (const float*)d_in[14];
  const float* p2  = (const float*)d_in[15];
  const float* p3  = (const float*)d_in[16];

  char* ws = (char*)d_ws;
  unsigned short* QH   = (unsigned short*)(ws);              //  8 MiB  [b][h][l][64] bf16
  unsigned short* KH   = (unsigned short*)(ws + 8388608);    //  8 MiB
  unsigned short* VH   = (unsigned short*)(ws + 16777216);   //  8 MiB
  unsigned short* VT   = (unsigned short*)(ws + 25165824);   //  8 MiB  [b][h][64][l]
  unsigned short* Omat = (unsigned short*)(ws + 33554432);   //  8 MiB  [b*l][512] bf16
  float* posi          = (float*)(ws + 41943040);            // 64 KiB
  float* Lrow          = (float*)(ws + 42008576);            // 256 KiB (1/l per row)
  // scratch2: preln (16 MiB) always; Pmat (128 MiB bf16) overlays it when ws
  // is big enough (disjoint lifetimes: Pmat dead before preln is written).
  char* scratch2       = ws + 42270720;
  float* preln         = (float*)scratch2;
  unsigned short* Pmat = (unsigned short*)scratch2;
  const bool bigws = ws_size >= (size_t)42270720 + (size_t)134217728;

  float* out0 = (float*)d_out;
  float* attn = out0 + (size_t)8 * 1024 * 512;

  posi_build<<<64, 256, 0, stream>>>(p0, p1, p2, p3, posi);
  // Q projection pre-scaled by log2(e)/sqrt(64) so attn uses exp2 directly.
  gemm512<0, false><<<dim3(64, 4), 256, 0, stream>>>(q, wqW, wqb, QH, 0.125f * LOG2E, nullptr, nullptr);
  gemm512<0, false><<<dim3(64, 4), 256, 0, stream>>>(k, wkW, wkb, KH, 1.f, nullptr, nullptr);
  gemm512<0, false><<<dim3(64, 4), 256, 0, stream>>>(v, wvW, wvb, VH, 1.f, nullptr, nullptr);
  transpose_v<<<dim3(16, 64), 256, 0, stream>>>(VH, VT);
  if (bigws) {
    attn_core<true><<<1024, 256, 0, stream>>>(QH, KH, VT, posi, Pmat, Lrow, Omat);
    attn_norm<false><<<2048, 256, 0, stream>>>(Pmat, Lrow, attn);
  } else {
    attn_core<false><<<1024, 256, 0, stream>>>(QH, KH, VT, posi, attn, Lrow, Omat);
    attn_norm<true><<<2048, 256, 0, stream>>>(nullptr, Lrow, attn);
  }
  gemm512<1, true><<<dim3(64, 4), 256, 0, stream>>>(Omat, fcW, fcb, nullptr, 1.f, q, preln);
  ln_fused<<<2048, 256, 0, stream>>>(preln, lng, lnb, out0);
}

// Round 8
// 273.143 us; speedup vs baseline: 1.1561x; 1.1035x over previous
//
#include <hip/hip_runtime.h>
#include <math.h>

// Problem constants: B=8, L=1024, D_MODEL=512, H=8, DK=DV=64.

typedef __attribute__((ext_vector_type(4))) float f32x4;
typedef __attribute__((ext_vector_type(8))) __bf16 bf8;
typedef __attribute__((ext_vector_type(8))) unsigned short us8;
typedef __attribute__((ext_vector_type(4))) unsigned short us4;

#define LOG2E 1.44269504088896f

static __device__ __forceinline__ unsigned short f2bf(float f) {
  union { float f; unsigned u; } x; x.f = f;
  unsigned r = x.u + 0x7fffu + ((x.u >> 16) & 1u);   // RNE
  return (unsigned short)(r >> 16);
}

static __device__ __forceinline__ float bf2f(unsigned short u) {
  union { unsigned u; float f; } x; x.u = ((unsigned)u) << 16;
  return x.f;
}

static __device__ __forceinline__ f32x4 mfma16(bf8 a, bf8 b, f32x4 c) {
  return __builtin_amdgcn_mfma_f32_16x16x32_bf16(a, b, c, 0, 0, 0);
}

// ---------------- posi(h, i-j) lookup table: [8][2048], idx = (i-j)+1023 ----
// Pre-multiplied by log2(e) so attention can use exp2 directly.
__global__ void posi_build(const float* __restrict__ p0, const float* __restrict__ p1,
                           const float* __restrict__ p2, const float* __restrict__ p3,
                           float* __restrict__ tab) {
  int idx = blockIdx.x * 256 + threadIdx.x;
  if (idx >= 8 * 2048) return;
  int h = idx >> 11, dd = idx & 2047;
  if (dd >= 2047) { tab[idx] = 0.f; return; }
  float d = (float)(dd - 1023);         // d = qi - kj
  float s = fabsf(d);
  float a1 = p1[h], a2 = p2[h];
  float sp1 = (a1 > 20.f) ? a1 : log1pf(expf(a1));
  float sp2 = (a2 > 20.f) ? a2 : log1pf(expf(a2));
  float asyn = (d < 0.f) ? 1.f : 0.f;   // qi < kj
  tab[idx] = p0[h] * (expf(-sp1 * s) + expf(-sp2 * s) + p3[h] * asyn) * LOG2E;
}

// ---------------- GEMM: C[m,o] = A[m,:] . W[o,:] (+bias, epilogue) ----------
// EPI=0: bf16 out to [b][h][l][d] (Q/K projections), scaled.
// EPI=1: fp32 out = acc + bias + resid (fc pre-LN).
// EPI=2: bf16 out to [b][h][d][l] (V projection, direct transpose).
template <int EPI, bool ABF>
__global__ __launch_bounds__(256) void gemm512(
    const void* __restrict__ Ap, const float* __restrict__ W,
    const float* __restrict__ bias, unsigned short* __restrict__ outb,
    float scale, const float* __restrict__ resid, float* __restrict__ outf) {
  __shared__ __align__(16) unsigned short As[128 * 32];
  __shared__ __align__(16) unsigned short Bs[128 * 32];
  const int tid = threadIdx.x;
  const int lane = tid & 63, w = tid >> 6;
  const int lg = lane >> 4, ln = lane & 15;
  const int wr = w >> 1, wc = w & 1;
  const int bm = blockIdx.x, bn = blockIdx.y;

  f32x4 acc[4][4] = {};

  for (int kt = 0; kt < 16; ++kt) {
    const int k0 = kt * 32;
    f32x4 areg[4]; us8 areg16[2]; f32x4 breg[4];
    if constexpr (!ABF) {
      const float* A = (const float*)Ap;
#pragma unroll
      for (int i = 0; i < 4; ++i) {
        int e = i * 1024 + tid * 4;
        int r = e >> 5, c = e & 31;
        areg[i] = *(const f32x4*)(A + (size_t)(bm * 128 + r) * 512 + k0 + c);
      }
    } else {
      const unsigned short* A = (const unsigned short*)Ap;
#pragma unroll
      for (int i = 0; i < 2; ++i) {
        int ch = i * 256 + tid;
        int r = ch >> 2, c = (ch & 3) * 8;
        areg16[i] = *(const us8*)(A + (size_t)(bm * 128 + r) * 512 + k0 + c);
      }
    }
#pragma unroll
    for (int i = 0; i < 4; ++i) {
      int e = i * 1024 + tid * 4;
      int r = e >> 5, c = e & 31;
      breg[i] = *(const f32x4*)(W + (size_t)(bn * 128 + r) * 512 + k0 + c);
    }
    __syncthreads();
    if constexpr (!ABF) {
#pragma unroll
      for (int i = 0; i < 4; ++i) {
        int e = i * 1024 + tid * 4;
        int r = e >> 5, c = e & 31;
        us4 u; u[0] = f2bf(areg[i][0]); u[1] = f2bf(areg[i][1]);
        u[2] = f2bf(areg[i][2]); u[3] = f2bf(areg[i][3]);
        *(us4*)&As[r * 32 + c] = u;
      }
    } else {
#pragma unroll
      for (int i = 0; i < 2; ++i) {
        int ch = i * 256 + tid;
        int r = ch >> 2, c = (ch & 3) * 8;
        *(us8*)&As[r * 32 + c] = areg16[i];
      }
    }
#pragma unroll
    for (int i = 0; i < 4; ++i) {
      int e = i * 1024 + tid * 4;
      int r = e >> 5, c = e & 31;
      us4 u; u[0] = f2bf(breg[i][0]); u[1] = f2bf(breg[i][1]);
      u[2] = f2bf(breg[i][2]); u[3] = f2bf(breg[i][3]);
      *(us4*)&Bs[r * 32 + c] = u;
    }
    __syncthreads();
    bf8 af[4], bfm[4];
#pragma unroll
    for (int m = 0; m < 4; ++m)
      af[m] = *(const bf8*)&As[(wr * 64 + m * 16 + ln) * 32 + lg * 8];
#pragma unroll
    for (int n = 0; n < 4; ++n)
      bfm[n] = *(const bf8*)&Bs[(wc * 64 + n * 16 + ln) * 32 + lg * 8];
#pragma unroll
    for (int m = 0; m < 4; ++m)
#pragma unroll
      for (int n = 0; n < 4; ++n)
        acc[m][n] = mfma16(af[m], bfm[n], acc[m][n]);
  }

#pragma unroll
  for (int m = 0; m < 4; ++m) {
#pragma unroll
    for (int n = 0; n < 4; ++n) {
      const int col = bn * 128 + wc * 64 + n * 16 + ln;
      const int row0 = bm * 128 + wr * 64 + m * 16 + lg * 4;
      const float bcol = bias[col];
#pragma unroll
      for (int r = 0; r < 4; ++r) {
        const int rg = row0 + r;
        float val = acc[m][n][r];
        if constexpr (EPI == 0) {
          val = (val + bcol) * scale;
          const int bb = rg >> 10, lq = rg & 1023, hh = col >> 6, dd = col & 63;
          outb[((size_t)(bb * 8 + hh) * 1024 + lq) * 64 + dd] = f2bf(val);
        } else if constexpr (EPI == 2) {
          val = (val + bcol) * scale;
          const int bb = rg >> 10, lq = rg & 1023, hh = col >> 6, dd = col & 63;
          outb[((size_t)(bb * 8 + hh) * 64 + dd) * 1024 + lq] = f2bf(val);
        } else {
          val = val + bcol + resid[(size_t)rg * 512 + col];
          outf[(size_t)rg * 512 + col] = val;
        }
      }
    }
  }
}

// ---------------- fused attention: LDS-resident P, single barrier ----------
// grid 2048: wgid = qblk*64 + bh (bh&7 = XCD -> L2-resident K/V slab).
// WG = 32 q-rows, 4 waves: wave (sp = w>>1 row-strip of 16, kh = w&1).
// Pass 1 (kj-split): QK^T (swapped: S[q=ln][kj=lg*4+r]) -> exp2 -> bf16 P
//   into pbuf LDS (chain TERMINATES at ds_write; iterations independent),
//   row sums -> lred.  BARRIER.
// Pass 1.5 (d-split, full kj): PV from pbuf; each wave owns 16 rows x 32
//   dims -> no cross-wave O combine. O fragment row = lg*4+r (NOT ln).
// Pass 2: streaming normalized attn store from pbuf (coalesced 1KB stores).
__global__ __launch_bounds__(256) void attn_fused(
    const unsigned short* __restrict__ QH, const unsigned short* __restrict__ KH,
    const unsigned short* __restrict__ VT, const float* __restrict__ posi_tab,
    float* __restrict__ attn_out, unsigned short* __restrict__ Omat) {
  __shared__ __align__(16) unsigned short pbuf[2][16][1048];  // 67 KB, pad->~2-way
  __shared__ float posi_w[1056];                              // 4.2 KB window
  __shared__ float lred[2][2][16];

  const int tid = threadIdx.x;
  const int lane = tid & 63, w = tid >> 6;
  const int lg = lane >> 4, ln = lane & 15;
  const int sp = w >> 1, kh = w & 1;
  const int wgid = blockIdx.x;
  const int bh = wgid & 63, qblk = wgid >> 6;   // qblk in [0,32)
  const int b = bh >> 3, h = bh & 7;
  const int q0 = qblk * 32;

  // posi window: posi(h, qi-kj) for qi in [q0,q0+32), kj in [0,1024)
  // global idx = (qi-kj)+1023 = q0 + local, local in [0,1056)
  for (int i = tid; i < 1056; i += 256) posi_w[i] = posi_tab[h * 2048 + q0 + i];
  __syncthreads();

  const size_t base = (size_t)(b * 8 + h) * 1024 * 64;
  const unsigned short* Qb = QH + base;
  const unsigned short* Kb = KH + base;
  const unsigned short* Vb = VT + base;

  const int qrow = sp * 16 + ln;          // scores-layout row within WG
  const unsigned short* qr = Qb + (size_t)(q0 + qrow) * 64 + lg * 8;
  const bf8 bq0 = *(const bf8*)qr;
  const bf8 bq1 = *(const bf8*)(qr + 32);

  // ---- PASS 1: P production over this wave's kj half ----
  const int kbase = kh << 9;
  f32x4 laccv = {0.f, 0.f, 0.f, 0.f};
  for (int kt = 0; kt < 8; ++kt) {
    const int k0 = kbase + kt * 64;
#pragma unroll
    for (int n = 0; n < 4; ++n) {
      const unsigned short* kr = Kb + (size_t)(k0 + n * 16 + ln) * 64 + lg * 8;
      bf8 a0 = *(const bf8*)kr;
      bf8 a1 = *(const bf8*)(kr + 32);
      f32x4 sc = {};
      sc = mfma16(a0, bq0, sc);
      sc = mfma16(a1, bq1, sc);
      const int kjb = k0 + n * 16 + lg * 4;        // kj of reg r = kjb + r
      const int pli = qrow - kjb + 1023;           // posi_w idx for r = pli - r
      us4 pb;
#pragma unroll
      for (int r = 0; r < 4; ++r) {
        float p = exp2f(sc[r] + posi_w[pli - r]);
        laccv[r] += p;
        pb[r] = f2bf(p);
      }
      *(us4*)&pbuf[sp][ln][kjb] = pb;              // ds_write_b64, chain ends
    }
  }
  float lacc = laccv[0] + laccv[1] + laccv[2] + laccv[3];
  lacc += __shfl_xor(lacc, 16, 64);
  lacc += __shfl_xor(lacc, 32, 64);
  if (lg == 0) lred[sp][kh][ln] = lacc;
  __syncthreads();                                  // P + lred complete

  // ---- PASS 1.5: PV, full kj, d-half = kh (no cross-wave combine) ----
  f32x4 oacc[2] = {};
  for (int kt = 0; kt < 16; ++kt) {
    const int k0 = kt * 64;
    const bf8 pa0 = *(const bf8*)&pbuf[sp][ln][k0 + lg * 8];
    const bf8 pa1 = *(const bf8*)&pbuf[sp][ln][k0 + 32 + lg * 8];
#pragma unroll
    for (int nn = 0; nn < 2; ++nn) {
      const int n = kh * 2 + nn;
      const unsigned short* vr = Vb + (size_t)(n * 16 + ln) * 1024 + k0 + lg * 8;
      bf8 v0 = *(const bf8*)vr;
      bf8 v1 = *(const bf8*)(vr + 32);
      oacc[nn] = mfma16(pa0, v0, oacc[nn]);
      oacc[nn] = mfma16(pa1, v1, oacc[nn]);
    }
  }
  // O fragment rows are lg*4+r: normalize per-register with that row's sum.
  f32x4 rlv;
#pragma unroll
  for (int r = 0; r < 4; ++r)
    rlv[r] = 1.f / (lred[sp][0][lg * 4 + r] + lred[sp][1][lg * 4 + r]);
#pragma unroll
  for (int nn = 0; nn < 2; ++nn) {
    const int n = kh * 2 + nn;
#pragma unroll
    for (int r = 0; r < 4; ++r)
      Omat[(size_t)(b * 1024 + q0 + sp * 16 + lg * 4 + r) * 512 +
           h * 64 + n * 16 + ln] = f2bf(oacc[nn][r] * rlv[r]);
  }

  // ---- PASS 2: streaming normalized attn store (rows of strip sp, half kh)
  float* abb = attn_out + (size_t)(h * 8 + b) * 1024 * 1024;
#pragma unroll 4
  for (int r = 0; r < 16; ++r) {
    const float rl = 1.f / (lred[sp][0][r] + lred[sp][1][r]);
    const size_t rowbase = (size_t)(q0 + sp * 16 + r) * 1024 + kh * 512;
#pragma unroll
    for (int j = 0; j < 2; ++j) {
      us4 pv = *(const us4*)&pbuf[sp][r][kh * 512 + j * 256 + lane * 4];
      f32x4 f0;
#pragma unroll
      for (int t = 0; t < 4; ++t) f0[t] = bf2f(pv[t]) * rl;
      *(f32x4*)(abb + rowbase + j * 256 + lane * 4) = f0;   // 1KB contiguous
    }
  }
}

// ---------------- LayerNorm over 512, one wave per row ---------------------
__global__ __launch_bounds__(256) void ln_fused(const float* __restrict__ x,
                                                const float* __restrict__ g,
                                                const float* __restrict__ bb,
                                                float* __restrict__ out) {
  const int lane = threadIdx.x & 63, w = threadIdx.x >> 6;
  const size_t row = (size_t)blockIdx.x * 4 + w;
  const float* xr = x + row * 512;
  f32x4 v0 = *(const f32x4*)(xr + lane * 8);
  f32x4 v1 = *(const f32x4*)(xr + lane * 8 + 4);
  float s = v0[0] + v0[1] + v0[2] + v0[3] + v1[0] + v1[1] + v1[2] + v1[3];
  float sq = v0[0] * v0[0] + v0[1] * v0[1] + v0[2] * v0[2] + v0[3] * v0[3] +
             v1[0] * v1[0] + v1[1] * v1[1] + v1[2] * v1[2] + v1[3] * v1[3];
#pragma unroll
  for (int msk = 1; msk <= 32; msk <<= 1) {
    s += __shfl_xor(s, msk, 64);
    sq += __shfl_xor(sq, msk, 64);
  }
  const float mu = s * (1.f / 512.f);
  const float var = sq * (1.f / 512.f) - mu * mu;
  const float rs = rsqrtf(var + 1e-5f);
  f32x4 g0 = *(const f32x4*)(g + lane * 8), g1 = *(const f32x4*)(g + lane * 8 + 4);
  f32x4 b0 = *(const f32x4*)(bb + lane * 8), b1 = *(const f32x4*)(bb + lane * 8 + 4);
  f32x4 o0, o1;
#pragma unroll
  for (int j = 0; j < 4; ++j) {
    o0[j] = (v0[j] - mu) * rs * g0[j] + b0[j];
    o1[j] = (v1[j] - mu) * rs * g1[j] + b1[j];
  }
  *(f32x4*)(out + row * 512 + lane * 8) = o0;
  *(f32x4*)(out + row * 512 + lane * 8 + 4) = o1;
}

extern "C" void kernel_launch(void* const* d_in, const int* in_sizes, int n_in,
                              void* d_out, int out_size, void* d_ws, size_t ws_size,
                              hipStream_t stream) {
  const float* q   = (const float*)d_in[0];
  const float* k   = (const float*)d_in[1];
  const float* v   = (const float*)d_in[2];
  const float* wqW = (const float*)d_in[3];
  const float* wqb = (const float*)d_in[4];
  const float* wkW = (const float*)d_in[5];
  const float* wkb = (const float*)d_in[6];
  const float* wvW = (const float*)d_in[7];
  const float* wvb = (const float*)d_in[8];
  const float* fcW = (const float*)d_in[9];
  const float* fcb = (const float*)d_in[10];
  const float* lng = (const float*)d_in[11];
  const float* lnb = (const float*)d_in[12];
  const float* p0  = (const float*)d_in[13];
  const float* p1  = (const float*)d_in[14];
  const float* p2  = (const float*)d_in[15];
  const float* p3  = (const float*)d_in[16];

  char* ws = (char*)d_ws;
  unsigned short* QH   = (unsigned short*)(ws);              //  8 MiB  [b][h][l][64]
  unsigned short* KH   = (unsigned short*)(ws + 8388608);    //  8 MiB  [b][h][l][64]
  unsigned short* VT   = (unsigned short*)(ws + 16777216);   //  8 MiB  [b][h][64][l]
  unsigned short* Omat = (unsigned short*)(ws + 25165824);   //  8 MiB  [b*l][512]
  float* posi          = (float*)(ws + 33554432);            // 64 KiB
  float* preln         = (float*)(ws + 33619968);            // 16 MiB fp32

  float* out0 = (float*)d_out;
  float* attn = out0 + (size_t)8 * 1024 * 512;

  posi_build<<<64, 256, 0, stream>>>(p0, p1, p2, p3, posi);
  // Q projection pre-scaled by log2(e)/sqrt(64) so attn uses exp2 directly.
  gemm512<0, false><<<dim3(64, 4), 256, 0, stream>>>(q, wqW, wqb, QH, 0.125f * LOG2E, nullptr, nullptr);
  gemm512<0, false><<<dim3(64, 4), 256, 0, stream>>>(k, wkW, wkb, KH, 1.f, nullptr, nullptr);
  gemm512<2, false><<<dim3(64, 4), 256, 0, stream>>>(v, wvW, wvb, VT, 1.f, nullptr, nullptr);
  attn_fused<<<2048, 256, 0, stream>>>(QH, KH, VT, posi, attn, Omat);
  gemm512<1, true><<<dim3(64, 4), 256, 0, stream>>>(Omat, fcW, fcb, nullptr, 1.f, q, preln);
  ln_fused<<<2048, 256, 0, stream>>>(preln, lng, lnb, out0);
}

// Round 9
// 255.078 us; speedup vs baseline: 1.2379x; 1.0708x over previous
//
#include <hip/hip_runtime.h>
#include <math.h>

// Problem constants: B=8, L=1024, D_MODEL=512, H=8, DK=DV=64.

typedef __attribute__((ext_vector_type(4))) float f32x4;
typedef __attribute__((ext_vector_type(8))) __bf16 bf8;
typedef __attribute__((ext_vector_type(8))) unsigned short us8;
typedef __attribute__((ext_vector_type(4))) unsigned short us4;

#define LOG2E 1.44269504088896f

static __device__ __forceinline__ unsigned short f2bf(float f) {
  union { float f; unsigned u; } x; x.f = f;
  unsigned r = x.u + 0x7fffu + ((x.u >> 16) & 1u);   // RNE
  return (unsigned short)(r >> 16);
}

static __device__ __forceinline__ float bf2f(unsigned short u) {
  union { unsigned u; float f; } x; x.u = ((unsigned)u) << 16;
  return x.f;
}

static __device__ __forceinline__ f32x4 mfma16(bf8 a, bf8 b, f32x4 c) {
  return __builtin_amdgcn_mfma_f32_16x16x32_bf16(a, b, c, 0, 0, 0);
}

// ---------------- posi(h, i-j) lookup table: [8][2048], idx = (i-j)+1023 ----
// Pre-multiplied by log2(e) so attention can use exp2 directly.
__global__ void posi_build(const float* __restrict__ p0, const float* __restrict__ p1,
                           const float* __restrict__ p2, const float* __restrict__ p3,
                           float* __restrict__ tab) {
  int idx = blockIdx.x * 256 + threadIdx.x;
  if (idx >= 8 * 2048) return;
  int h = idx >> 11, dd = idx & 2047;
  if (dd >= 2047) { tab[idx] = 0.f; return; }
  float d = (float)(dd - 1023);         // d = qi - kj
  float s = fabsf(d);
  float a1 = p1[h], a2 = p2[h];
  float sp1 = (a1 > 20.f) ? a1 : log1pf(expf(a1));
  float sp2 = (a2 > 20.f) ? a2 : log1pf(expf(a2));
  float asyn = (d < 0.f) ? 1.f : 0.f;   // qi < kj
  tab[idx] = p0[h] * (expf(-sp1 * s) + expf(-sp2 * s) + p3[h] * asyn) * LOG2E;
}

// ---------------- GEMM: C[m,o] = A[m,:] . W[o,:] (+bias, epilogue) ----------
// EPI=0: bf16 out to [b][h][l][d] (Q/K projections), scaled.
// EPI=1: fp32 out = acc + bias + resid (fc pre-LN).
// EPI=2: bf16 out to [b][h][d][l] (V projection, direct transpose).
template <int EPI, bool ABF>
__global__ __launch_bounds__(256) void gemm512(
    const void* __restrict__ Ap, const float* __restrict__ W,
    const float* __restrict__ bias, unsigned short* __restrict__ outb,
    float scale, const float* __restrict__ resid, float* __restrict__ outf) {
  __shared__ __align__(16) unsigned short As[128 * 32];
  __shared__ __align__(16) unsigned short Bs[128 * 32];
  const int tid = threadIdx.x;
  const int lane = tid & 63, w = tid >> 6;
  const int lg = lane >> 4, ln = lane & 15;
  const int wr = w >> 1, wc = w & 1;
  const int bm = blockIdx.x, bn = blockIdx.y;

  f32x4 acc[4][4] = {};

  for (int kt = 0; kt < 16; ++kt) {
    const int k0 = kt * 32;
    f32x4 areg[4]; us8 areg16[2]; f32x4 breg[4];
    if constexpr (!ABF) {
      const float* A = (const float*)Ap;
#pragma unroll
      for (int i = 0; i < 4; ++i) {
        int e = i * 1024 + tid * 4;
        int r = e >> 5, c = e & 31;
        areg[i] = *(const f32x4*)(A + (size_t)(bm * 128 + r) * 512 + k0 + c);
      }
    } else {
      const unsigned short* A = (const unsigned short*)Ap;
#pragma unroll
      for (int i = 0; i < 2; ++i) {
        int ch = i * 256 + tid;
        int r = ch >> 2, c = (ch & 3) * 8;
        areg16[i] = *(const us8*)(A + (size_t)(bm * 128 + r) * 512 + k0 + c);
      }
    }
#pragma unroll
    for (int i = 0; i < 4; ++i) {
      int e = i * 1024 + tid * 4;
      int r = e >> 5, c = e & 31;
      breg[i] = *(const f32x4*)(W + (size_t)(bn * 128 + r) * 512 + k0 + c);
    }
    __syncthreads();
    if constexpr (!ABF) {
#pragma unroll
      for (int i = 0; i < 4; ++i) {
        int e = i * 1024 + tid * 4;
        int r = e >> 5, c = e & 31;
        us4 u; u[0] = f2bf(areg[i][0]); u[1] = f2bf(areg[i][1]);
        u[2] = f2bf(areg[i][2]); u[3] = f2bf(areg[i][3]);
        *(us4*)&As[r * 32 + c] = u;
      }
    } else {
#pragma unroll
      for (int i = 0; i < 2; ++i) {
        int ch = i * 256 + tid;
        int r = ch >> 2, c = (ch & 3) * 8;
        *(us8*)&As[r * 32 + c] = areg16[i];
      }
    }
#pragma unroll
    for (int i = 0; i < 4; ++i) {
      int e = i * 1024 + tid * 4;
      int r = e >> 5, c = e & 31;
      us4 u; u[0] = f2bf(breg[i][0]); u[1] = f2bf(breg[i][1]);
      u[2] = f2bf(breg[i][2]); u[3] = f2bf(breg[i][3]);
      *(us4*)&Bs[r * 32 + c] = u;
    }
    __syncthreads();
    bf8 af[4], bfm[4];
#pragma unroll
    for (int m = 0; m < 4; ++m)
      af[m] = *(const bf8*)&As[(wr * 64 + m * 16 + ln) * 32 + lg * 8];
#pragma unroll
    for (int n = 0; n < 4; ++n)
      bfm[n] = *(const bf8*)&Bs[(wc * 64 + n * 16 + ln) * 32 + lg * 8];
#pragma unroll
    for (int m = 0; m < 4; ++m)
#pragma unroll
      for (int n = 0; n < 4; ++n)
        acc[m][n] = mfma16(af[m], bfm[n], acc[m][n]);
  }

#pragma unroll
  for (int m = 0; m < 4; ++m) {
#pragma unroll
    for (int n = 0; n < 4; ++n) {
      const int col = bn * 128 + wc * 64 + n * 16 + ln;
      const int row0 = bm * 128 + wr * 64 + m * 16 + lg * 4;
      const float bcol = bias[col];
#pragma unroll
      for (int r = 0; r < 4; ++r) {
        const int rg = row0 + r;
        float val = acc[m][n][r];
        if constexpr (EPI == 0) {
          val = (val + bcol) * scale;
          const int bb = rg >> 10, lq = rg & 1023, hh = col >> 6, dd = col & 63;
          outb[((size_t)(bb * 8 + hh) * 1024 + lq) * 64 + dd] = f2bf(val);
        } else if constexpr (EPI == 2) {
          val = (val + bcol) * scale;
          const int bb = rg >> 10, lq = rg & 1023, hh = col >> 6, dd = col & 63;
          outb[((size_t)(bb * 8 + hh) * 64 + dd) * 1024 + lq] = f2bf(val);
        } else {
          val = val + bcol + resid[(size_t)rg * 512 + col];
          outf[(size_t)rg * 512 + col] = val;
        }
      }
    }
  }
}

// ---------------- fused attention: LDS-resident P, 8 waves -----------------
// grid 2048: wgid = qblk*64 + bh (bh&7 = XCD swizzle; working set is
// L3-resident, NOT L2 -- per-XCD footprint ~48MB vs 4MB L2).
// WG = 32 q-rows, 512 threads = 8 waves (4 waves/SIMD vs R8's 2: the point
// of this round -- TLP to hide the ~500cy L3 load latency).
// Pass 1: wave (sp = w>>2 row-strip of 16, kq = w&3 kj-quarter of 256):
//   swapped QK^T (S[q=ln][kj=lg*4+r]) -> exp2 -> bf16 P into pbuf, row sums
//   into lred[sp][kq][row].  BARRIER.
// Pass 1.5: wave (sp, dq = w&3 d-quarter of 16): PV over full kj from pbuf;
//   O fragment row = lg*4+r (NOT ln) -> normalize per-register.
// Pass 2: wave (sp, kq): streaming normalized attn store (1KB coalesced).
__global__ __launch_bounds__(512) void attn_fused(
    const unsigned short* __restrict__ QH, const unsigned short* __restrict__ KH,
    const unsigned short* __restrict__ VT, const float* __restrict__ posi_tab,
    float* __restrict__ attn_out, unsigned short* __restrict__ Omat) {
  __shared__ __align__(16) unsigned short pbuf[2][16][1048];  // 67 KB, pad->~2-way
  __shared__ float posi_w[1056];                              // 4.2 KB window
  __shared__ float lred[2][4][16];

  const int tid = threadIdx.x;
  const int lane = tid & 63, w = tid >> 6;
  const int lg = lane >> 4, ln = lane & 15;
  const int sp = w >> 2, kq = w & 3;            // kq doubles as dq in pass 1.5
  const int wgid = blockIdx.x;
  const int bh = wgid & 63, qblk = wgid >> 6;   // qblk in [0,32)
  const int b = bh >> 3, h = bh & 7;
  const int q0 = qblk * 32;

  // posi window: posi(h, qi-kj) for qi in [q0,q0+32), kj in [0,1024)
  for (int i = tid; i < 1056; i += 512) posi_w[i] = posi_tab[h * 2048 + q0 + i];
  __syncthreads();

  const size_t base = (size_t)(b * 8 + h) * 1024 * 64;
  const unsigned short* Qb = QH + base;
  const unsigned short* Kb = KH + base;
  const unsigned short* Vb = VT + base;

  const int qrow = sp * 16 + ln;          // scores-layout row within WG
  const unsigned short* qr = Qb + (size_t)(q0 + qrow) * 64 + lg * 8;
  const bf8 bq0 = *(const bf8*)qr;
  const bf8 bq1 = *(const bf8*)(qr + 32);

  // ---- PASS 1: P production over this wave's kj quarter (256 kj) ----
  const int kbase = kq << 8;
  f32x4 laccv = {0.f, 0.f, 0.f, 0.f};
  for (int kt = 0; kt < 4; ++kt) {
    const int k0 = kbase + kt * 64;
#pragma unroll
    for (int n = 0; n < 4; ++n) {
      const unsigned short* kr = Kb + (size_t)(k0 + n * 16 + ln) * 64 + lg * 8;
      bf8 a0 = *(const bf8*)kr;
      bf8 a1 = *(const bf8*)(kr + 32);
      f32x4 sc = {};
      sc = mfma16(a0, bq0, sc);
      sc = mfma16(a1, bq1, sc);
      const int kjb = k0 + n * 16 + lg * 4;        // kj of reg r = kjb + r
      const int pli = qrow - kjb + 1023;           // posi_w idx for r = pli - r
      us4 pb;
#pragma unroll
      for (int r = 0; r < 4; ++r) {
        float p = exp2f(sc[r] + posi_w[pli - r]);
        laccv[r] += p;
        pb[r] = f2bf(p);
      }
      *(us4*)&pbuf[sp][ln][kjb] = pb;              // ds_write_b64, chain ends
    }
  }
  float lacc = laccv[0] + laccv[1] + laccv[2] + laccv[3];
  lacc += __shfl_xor(lacc, 16, 64);
  lacc += __shfl_xor(lacc, 32, 64);
  if (lg == 0) lred[sp][kq][ln] = lacc;
  __syncthreads();                                  // P + lred complete

  // ---- PASS 1.5: PV, full kj, d-quarter = kq (no cross-wave combine) ----
  f32x4 oacc = {};
  for (int kt = 0; kt < 16; ++kt) {
    const int k0 = kt * 64;
    const bf8 pa0 = *(const bf8*)&pbuf[sp][ln][k0 + lg * 8];
    const bf8 pa1 = *(const bf8*)&pbuf[sp][ln][k0 + 32 + lg * 8];
    const unsigned short* vr = Vb + (size_t)(kq * 16 + ln) * 1024 + k0 + lg * 8;
    bf8 v0 = *(const bf8*)vr;
    bf8 v1 = *(const bf8*)(vr + 32);
    oacc = mfma16(pa0, v0, oacc);
    oacc = mfma16(pa1, v1, oacc);
  }
  // O fragment rows are lg*4+r: normalize per-register with that row's sum.
#pragma unroll
  for (int r = 0; r < 4; ++r) {
    const int row = lg * 4 + r;
    const float rl = 1.f / (lred[sp][0][row] + lred[sp][1][row] +
                            lred[sp][2][row] + lred[sp][3][row]);
    Omat[(size_t)(b * 1024 + q0 + sp * 16 + row) * 512 +
         h * 64 + kq * 16 + ln] = f2bf(oacc[r] * rl);
  }

  // ---- PASS 2: streaming normalized attn store (strip sp, quarter kq) ----
  float* abb = attn_out + (size_t)(h * 8 + b) * 1024 * 1024;
#pragma unroll 4
  for (int r = 0; r < 16; ++r) {
    const float rl = 1.f / (lred[sp][0][r] + lred[sp][1][r] +
                            lred[sp][2][r] + lred[sp][3][r]);
    const size_t rowbase = (size_t)(q0 + sp * 16 + r) * 1024 + kq * 256;
    us4 pv = *(const us4*)&pbuf[sp][r][kq * 256 + lane * 4];
    f32x4 f0;
#pragma unroll
    for (int t = 0; t < 4; ++t) f0[t] = bf2f(pv[t]) * rl;
    *(f32x4*)(abb + rowbase + lane * 4) = f0;       // 1KB contiguous
  }
}

// ---------------- LayerNorm over 512, one wave per row ---------------------
__global__ __launch_bounds__(256) void ln_fused(const float* __restrict__ x,
                                                const float* __restrict__ g,
                                                const float* __restrict__ bb,
                                                float* __restrict__ out) {
  const int lane = threadIdx.x & 63, w = threadIdx.x >> 6;
  const size_t row = (size_t)blockIdx.x * 4 + w;
  const float* xr = x + row * 512;
  f32x4 v0 = *(const f32x4*)(xr + lane * 8);
  f32x4 v1 = *(const f32x4*)(xr + lane * 8 + 4);
  float s = v0[0] + v0[1] + v0[2] + v0[3] + v1[0] + v1[1] + v1[2] + v1[3];
  float sq = v0[0] * v0[0] + v0[1] * v0[1] + v0[2] * v0[2] + v0[3] * v0[3] +
             v1[0] * v1[0] + v1[1] * v1[1] + v1[2] * v1[2] + v1[3] * v1[3];
#pragma unroll
  for (int msk = 1; msk <= 32; msk <<= 1) {
    s += __shfl_xor(s, msk, 64);
    sq += __shfl_xor(sq, msk, 64);
  }
  const float mu = s * (1.f / 512.f);
  const float var = sq * (1.f / 512.f) - mu * mu;
  const float rs = rsqrtf(var + 1e-5f);
  f32x4 g0 = *(const f32x4*)(g + lane * 8), g1 = *(const f32x4*)(g + lane * 8 + 4);
  f32x4 b0 = *(const f32x4*)(bb + lane * 8), b1 = *(const f32x4*)(bb + lane * 8 + 4);
  f32x4 o0, o1;
#pragma unroll
  for (int j = 0; j < 4; ++j) {
    o0[j] = (v0[j] - mu) * rs * g0[j] + b0[j];
    o1[j] = (v1[j] - mu) * rs * g1[j] + b1[j];
  }
  *(f32x4*)(out + row * 512 + lane * 8) = o0;
  *(f32x4*)(out + row * 512 + lane * 8 + 4) = o1;
}

extern "C" void kernel_launch(void* const* d_in, const int* in_sizes, int n_in,
                              void* d_out, int out_size, void* d_ws, size_t ws_size,
                              hipStream_t stream) {
  const float* q   = (const float*)d_in[0];
  const float* k   = (const float*)d_in[1];
  const float* v   = (const float*)d_in[2];
  const float* wqW = (const float*)d_in[3];
  const float* wqb = (const float*)d_in[4];
  const float* wkW = (const float*)d_in[5];
  const float* wkb = (const float*)d_in[6];
  const float* wvW = (const float*)d_in[7];
  const float* wvb = (const float*)d_in[8];
  const float* fcW = (const float*)d_in[9];
  const float* fcb = (const float*)d_in[10];
  const float* lng = (const float*)d_in[11];
  const float* lnb = (const float*)d_in[12];
  const float* p0  = (const float*)d_in[13];
  const float* p1  = (const float*)d_in[14];
  const float* p2  = (const float*)d_in[15];
  const float* p3  = (const float*)d_in[16];

  char* ws = (char*)d_ws;
  unsigned short* QH   = (unsigned short*)(ws);              //  8 MiB  [b][h][l][64]
  unsigned short* KH   = (unsigned short*)(ws + 8388608);    //  8 MiB  [b][h][l][64]
  unsigned short* VT   = (unsigned short*)(ws + 16777216);   //  8 MiB  [b][h][64][l]
  unsigned short* Omat = (unsigned short*)(ws + 25165824);   //  8 MiB  [b*l][512]
  float* posi          = (float*)(ws + 33554432);            // 64 KiB
  float* preln         = (float*)(ws + 33619968);            // 16 MiB fp32

  float* out0 = (float*)d_out;
  float* attn = out0 + (size_t)8 * 1024 * 512;

  posi_build<<<64, 256, 0, stream>>>(p0, p1, p2, p3, posi);
  // Q projection pre-scaled by log2(e)/sqrt(64) so attn uses exp2 directly.
  gemm512<0, false><<<dim3(64, 4), 256, 0, stream>>>(q, wqW, wqb, QH, 0.125f * LOG2E, nullptr, nullptr);
  gemm512<0, false><<<dim3(64, 4), 256, 0, stream>>>(k, wkW, wkb, KH, 1.f, nullptr, nullptr);
  gemm512<2, false><<<dim3(64, 4), 256, 0, stream>>>(v, wvW, wvb, VT, 1.f, nullptr, nullptr);
  attn_fused<<<2048, 512, 0, stream>>>(QH, KH, VT, posi, attn, Omat);
  gemm512<1, true><<<dim3(64, 4), 256, 0, stream>>>(Omat, fcW, fcb, nullptr, 1.f, q, preln);
  ln_fused<<<2048, 256, 0, stream>>>(preln, lng, lnb, out0);
}